// Round 7
// baseline (876.430 us; speedup 1.0000x reference)
//
#include <hip/hip_runtime.h>
#include <hip/hip_bf16.h>
#include <hip/hip_cooperative_groups.h>

namespace cg = cooperative_groups;

// Problem constants (from reference)
#define D_EMB    512
#define D4       128                 // D_EMB/4 float4 per row
#define NCOMP    1024
#define NDOSE    8
#define NSEG     (NCOMP * NDOSE)     // 8192
#define MARGIN_F 0.1f

typedef unsigned int uint32;

// ---------------------------------------------------------------------------
// Kernel A (cooperative): zero -> histogram -> scan -> scatter.
// 256 blocks x 1024 threads = 262144 threads (== N): one row per thread.
// __launch_bounds__(1024,4) caps VGPR at 128 -> 1 block/CU co-residency
// guaranteed for the cooperative launch.
// ---------------------------------------------------------------------------
__global__ __launch_bounds__(1024, 4) void sort_coop_kernel(
    const int* __restrict__ comp, const int* __restrict__ dose,
    uint32* __restrict__ hist, float* __restrict__ mu_sum,
    uint32* __restrict__ off, uint32* __restrict__ cur,
    uint32* __restrict__ perm, int n)
{
    cg::grid_group grid = cg::this_grid();
    const int tid = blockIdx.x * blockDim.x + threadIdx.x;
    const int nth = gridDim.x * blockDim.x;

    // phase 0: zero accumulators (d_ws is poisoned 0xAA before every call)
    for (int i = tid; i < NSEG; i += nth) hist[i] = 0u;
    if (tid < D_EMB) mu_sum[tid] = 0.f;
    grid.sync();

    // phase 1: histogram (global atomics, ~32 collisions/address)
    for (int r = tid; r < n; r += nth)
        atomicAdd(&hist[comp[r] * NDOSE + dose[r]], 1u);
    grid.sync();

    // phase 2: exclusive scan of hist[8192] -> off, cur (block 0 only)
    __shared__ uint32 sums[1024];
    if (blockIdx.x == 0) {
        const int t = threadIdx.x;
        uint32 v[8];
        uint32 tot = 0;
        #pragma unroll
        for (int j = 0; j < 8; ++j) { v[j] = hist[t * 8 + j]; tot += v[j]; }
        sums[t] = tot;
        __syncthreads();
        for (int o = 1; o < 1024; o <<= 1) {
            uint32 add = (t >= o) ? sums[t - o] : 0u;
            __syncthreads();
            sums[t] += add;
            __syncthreads();
        }
        uint32 run = sums[t] - tot;
        #pragma unroll
        for (int j = 0; j < 8; ++j) {
            off[t * 8 + j] = run;
            cur[t * 8 + j] = run;
            run += v[j];
        }
    }
    grid.sync();

    // phase 3: scatter row indices into segment-sorted order
    for (int r = tid; r < n; r += nth) {
        const int s = comp[r] * NDOSE + dose[r];
        const uint32 pos = atomicAdd(&cur[s], 1u);
        perm[pos] = (uint32)r;
    }
}

// ---------------------------------------------------------------------------
// segsum: per-segment vector sums S[s][512]. One block per segment,
// atomic-free. 256 threads = 128 float4 cols x 2 row-subgroups.
// THE 512 MiB pass — kept as a normal full-occupancy launch.
// ---------------------------------------------------------------------------
#define PERM_LDS 128
__global__ __launch_bounds__(256) void segsum_kernel(
    const float* __restrict__ emb, const uint32* __restrict__ off,
    const uint32* __restrict__ hist, const uint32* __restrict__ perm,
    float* __restrict__ S)
{
    const int s    = blockIdx.x;
    const int c4   = threadIdx.x & 127;
    const int rsub = threadIdx.x >> 7;
    const uint32 beg = off[s];
    const uint32 cnt = hist[s];
    const float4* __restrict__ E = (const float4*)emb;

    __shared__ uint32 lperm[PERM_LDS];
    const uint32 staged = (cnt < (uint32)PERM_LDS) ? cnt : (uint32)PERM_LDS;
    for (uint32 i = threadIdx.x; i < staged; i += blockDim.x)
        lperm[i] = perm[beg + i];
    __syncthreads();

    float4 acc = make_float4(0.f, 0.f, 0.f, 0.f);
    uint32 i = (uint32)rsub;
    for (; i < staged; i += 2) {
        const uint32 r = lperm[i];
        const float4 v = E[(size_t)r * D4 + c4];
        acc.x += v.x; acc.y += v.y; acc.z += v.z; acc.w += v.w;
    }
    for (; i < cnt; i += 2) {    // tail fallback (cnt > 128: essentially never)
        const uint32 r = perm[beg + i];
        const float4 v = E[(size_t)r * D4 + c4];
        acc.x += v.x; acc.y += v.y; acc.z += v.z; acc.w += v.w;
    }

    __shared__ float4 part[256];
    part[threadIdx.x] = acc;
    __syncthreads();
    if (threadIdx.x < 128) {
        const float4 a = part[threadIdx.x];
        const float4 b = part[threadIdx.x + 128];
        float4 o;
        o.x = a.x + b.x; o.y = a.y + b.y; o.z = a.z + b.z; o.w = a.w + b.w;
        ((float4*)S)[(size_t)s * D4 + c4] = o;
    }
}

// ---------------------------------------------------------------------------
// Kernel B (cooperative): musum -> dot (per-wave origin) -> epilogue.
// 256 blocks x 1024 threads, 1 block/CU co-resident.
// ---------------------------------------------------------------------------
__global__ __launch_bounds__(1024, 4) void finish_coop_kernel(
    const float* __restrict__ S, const uint32* __restrict__ hist,
    float* __restrict__ mu_sum, float* __restrict__ seg_mean,
    float* __restrict__ out, float inv_n)
{
    cg::grid_group grid = cg::this_grid();
    __shared__ float4 part4[1024];   // 16 KB; epilogue reuses as 2x float[1024]
    const float4* __restrict__ S4 = (const float4*)S;

    // phase 1: mu_sum[512] = column sums of S (LDS-reduced, atomic merge)
    {
        const int c4  = threadIdx.x & 127;
        const int sub = threadIdx.x >> 7;      // 0..7
        float4 acc = make_float4(0.f, 0.f, 0.f, 0.f);
        for (int s = blockIdx.x * 8 + sub; s < NSEG; s += gridDim.x * 8) {
            const float4 v = S4[(size_t)s * D4 + c4];
            acc.x += v.x; acc.y += v.y; acc.z += v.z; acc.w += v.w;
        }
        part4[threadIdx.x] = acc;
        __syncthreads();
        if (threadIdx.x < 128) {
            float4 a = part4[threadIdx.x];
            #pragma unroll
            for (int sb = 1; sb < 8; ++sb) {
                const float4 b = part4[threadIdx.x + 128 * sb];
                a.x += b.x; a.y += b.y; a.z += b.z; a.w += b.w;
            }
            const int c = threadIdx.x * 4;
            atomicAdd(&mu_sum[c + 0], a.x);
            atomicAdd(&mu_sum[c + 1], a.y);
            atomicAdd(&mu_sum[c + 2], a.z);
            atomicAdd(&mu_sum[c + 3], a.w);
        }
    }
    grid.sync();

    // phase 2: seg_mean[s] = (cnt_s - S_s . origin) / max(cnt_s, 1)
    // origin recomputed per-wave from mu_sum (cheap, L2-resident).
    {
        const int lane  = threadIdx.x & 63;
        const int wglob = blockIdx.x * (int)(blockDim.x >> 6) + (threadIdx.x >> 6);
        const int wtot  = gridDim.x * (int)(blockDim.x >> 6);

        const float4* __restrict__ MU = (const float4*)mu_sum;
        float4 m0 = MU[lane];
        float4 m1 = MU[lane + 64];
        m0.x *= inv_n; m0.y *= inv_n; m0.z *= inv_n; m0.w *= inv_n;
        m1.x *= inv_n; m1.y *= inv_n; m1.z *= inv_n; m1.w *= inv_n;
        float sq = m0.x * m0.x + m0.y * m0.y + m0.z * m0.z + m0.w * m0.w
                 + m1.x * m1.x + m1.y * m1.y + m1.z * m1.z + m1.w * m1.w;
        #pragma unroll
        for (int o = 32; o; o >>= 1) sq += __shfl_xor(sq, o, 64);
        const float inv_norm = 1.0f / fmaxf(sqrtf(sq), 1e-12f);
        float4 o0, o1;
        o0.x = m0.x * inv_norm; o0.y = m0.y * inv_norm;
        o0.z = m0.z * inv_norm; o0.w = m0.w * inv_norm;
        o1.x = m1.x * inv_norm; o1.y = m1.y * inv_norm;
        o1.z = m1.z * inv_norm; o1.w = m1.w * inv_norm;

        for (int s = wglob; s < NSEG; s += wtot) {
            const float4 v0 = S4[(size_t)s * D4 + lane];
            const float4 v1 = S4[(size_t)s * D4 + lane + 64];
            float p = v0.x * o0.x + v0.y * o0.y + v0.z * o0.z + v0.w * o0.w
                    + v1.x * o1.x + v1.y * o1.y + v1.z * o1.z + v1.w * o1.w;
            #pragma unroll
            for (int o = 32; o; o >>= 1) p += __shfl_xor(p, o, 64);
            if (lane == 0) {
                const float cntf = (float)hist[s];
                seg_mean[s] = (cntf - p) / fmaxf(cntf, 1.f);
            }
        }
    }
    grid.sync();

    // phase 3: ordinal margin epilogue -> scalar (block 0, 1024 threads)
    if (blockIdx.x == 0) {
        float* sl = (float*)part4;       // reuse LDS
        float* sc = sl + 1024;
        const int c = threadIdx.x;       // compound id
        float loss = 0.f, cntv = 0.f;
        {
            float last_mean = 0.f;
            bool  last_valid = false;
            #pragma unroll
            for (int d = 0; d < NDOSE; ++d) {
                const bool  pres = hist[c * NDOSE + d] > 0u;
                const float mean = seg_mean[c * NDOSE + d];
                if (pres && last_valid) {
                    loss += fmaxf(MARGIN_F - (mean - last_mean), 0.f);
                    cntv += 1.f;
                }
                if (pres) { last_mean = mean; last_valid = true; }
            }
        }
        sl[c] = loss; sc[c] = cntv;
        __syncthreads();
        #pragma unroll
        for (int o = 512; o; o >>= 1) {
            if (c < o) { sl[c] += sl[c + o]; sc[c] += sc[c + o]; }
            __syncthreads();
        }
        if (c == 0) out[0] = (sc[0] > 0.f) ? (sl[0] / fmaxf(sc[0], 1.f)) : 0.f;
    }
}

// ---------------------------------------------------------------------------
extern "C" void kernel_launch(void* const* d_in, const int* in_sizes, int n_in,
                              void* d_out, int out_size, void* d_ws, size_t ws_size,
                              hipStream_t stream)
{
    const float* emb  = (const float*)d_in[0];
    const int*   comp = (const int*)d_in[1];
    const int*   dose = (const int*)d_in[2];
    float*       out  = (float*)d_out;
    int n = in_sizes[1];

    // workspace layout:
    //   hist[8192]u32 | mu_sum[512]f | off[8192]u32 | cur[8192]u32 |
    //   perm[n]u32 | seg_mean[8192]f | (pad 512f) | S[8192*512]f
    uint32* hist    = (uint32*)d_ws;
    float*  mu_sum  = (float*)(hist + NSEG);
    uint32* off     = (uint32*)(mu_sum + D_EMB);
    uint32* cur     = off + NSEG;
    uint32* perm    = cur + NSEG;
    float*  seg_mean= (float*)(perm + n);
    float*  S       = seg_mean + NSEG + D_EMB;

    float inv_n = 1.0f / (float)n;

    {
        void* argsA[] = { (void*)&comp, (void*)&dose, (void*)&hist,
                          (void*)&mu_sum, (void*)&off, (void*)&cur,
                          (void*)&perm, (void*)&n };
        hipLaunchCooperativeKernel((const void*)sort_coop_kernel,
                                   dim3(256), dim3(1024), argsA, 0, stream);
    }

    segsum_kernel<<<NSEG, 256, 0, stream>>>(emb, off, hist, perm, S);

    {
        void* argsB[] = { (void*)&S, (void*)&hist, (void*)&mu_sum,
                          (void*)&seg_mean, (void*)&out, (void*)&inv_n };
        hipLaunchCooperativeKernel((const void*)finish_coop_kernel,
                                   dim3(256), dim3(1024), argsB, 0, stream);
    }
}